// Round 26
// baseline (366.139 us; speedup 1.0000x reference)
//
#include <hip/hip_runtime.h>

typedef unsigned short u16;
typedef __bf16 bf16x8 __attribute__((ext_vector_type(8)));
typedef float f32x4 __attribute__((ext_vector_type(4)));
typedef u16 u16x4 __attribute__((ext_vector_type(4)));

constexpr int SEQ = 2048;
constexpr int NQKV = 6144; // (32 + 2*8) * 128

__device__ __forceinline__ float bf2f(u16 x) {
    unsigned int u = ((unsigned int)x) << 16;
    return __builtin_bit_cast(float, u);
}
__device__ __forceinline__ u16 f2bf(float f) {
    unsigned int u = __builtin_bit_cast(unsigned int, f);
    u += 0x7FFF + ((u >> 16) & 1);
    return (u16)(u >> 16);
}

__device__ __forceinline__ void gload16(const void* g, void* l) {
    void* gg = const_cast<void*>(g);
    __builtin_amdgcn_global_load_lds(
        (__attribute__((address_space(1))) void*)gg,
        (__attribute__((address_space(3))) void*)l, 16, 0, 0);
}

// counted-vmcnt gate + raw barrier
__device__ __forceinline__ void gatebar(int G) {
    if (G == 8) asm volatile("s_waitcnt vmcnt(8)" ::: "memory");
    else if (G == 6) asm volatile("s_waitcnt vmcnt(6)" ::: "memory");
    else if (G == 4) asm volatile("s_waitcnt vmcnt(4)" ::: "memory");
    else asm volatile("s_waitcnt vmcnt(0)" ::: "memory");
    __builtin_amdgcn_sched_barrier(0);
    __builtin_amdgcn_s_barrier();
    __builtin_amdgcn_sched_barrier(0);
}

// ---- fp32 transpose+cast body (R x C fp32 -> C x R bf16), 64x64 tile ----
__device__ __forceinline__ void transpose_cast_body(const float* __restrict__ src,
                                                    u16* __restrict__ dst, int R, int C,
                                                    int bx, int by, int t) {
    __shared__ u16 tile[64][65];
    int r0 = by * 64, c0 = bx * 64;
#pragma unroll
    for (int it = 0; it < 4; ++it) {
        int row = it * 16 + (t >> 4);
        int col = (t & 15) * 4;
        f32x4 v = *(const f32x4*)&src[(size_t)(r0 + row) * C + c0 + col];
        tile[row][col] = f2bf(v[0]); tile[row][col + 1] = f2bf(v[1]);
        tile[row][col + 2] = f2bf(v[2]); tile[row][col + 3] = f2bf(v[3]);
    }
    __syncthreads();
#pragma unroll
    for (int it = 0; it < 4; ++it) {
        int orow = it * 16 + (t >> 4);
        int ocol = (t & 15) * 4;
        u16x4 v;
        v[0] = tile[ocol][orow]; v[1] = tile[ocol + 1][orow];
        v[2] = tile[ocol + 2][orow]; v[3] = tile[ocol + 3][orow];
        *(u16x4*)&dst[(size_t)(c0 + orow) * R + r0 + ocol] = v;
    }
}

// ==== FUSED PRE: cast(8192) | transposeWqkv(6144: 96x64) | rope_table(512) ====
__global__ __launch_bounds__(256) void pre_fused_k(const float* __restrict__ hidden,
                                                   u16* __restrict__ hiddenB,
                                                   const float* __restrict__ Wqkv,
                                                   u16* __restrict__ WqkvT,
                                                   float* __restrict__ tab) {
    int b = blockIdx.x;
    int t = threadIdx.x;
    if (b < 8192) {
        int i = b * 256 + t;
        f32x4 v = *(const f32x4*)&hidden[(size_t)i * 4];
        u16x4 o;
#pragma unroll
        for (int j = 0; j < 4; ++j) o[j] = f2bf(v[j]);
        *(u16x4*)&hiddenB[(size_t)i * 4] = o;
    } else if (b < 8192 + 6144) {
        int r = b - 8192;
        transpose_cast_body(Wqkv, WqkvT, 4096, 6144, r % 96, r / 96, t);
    } else {
        int idx = (b - 14336) * 256 + t;
        if (idx < SEQ * 64) {
            int s = idx >> 6;
            int i = idx & 63;
            float invf = expf(-(float)i * (float)(1.0 / 64.0) * logf(10000.0f));
            float ang = (float)s * invf;
            float sv, cv;
            sincosf(ang, &sv, &cv);
            tab[idx * 2] = cv;
            tab[idx * 2 + 1] = sv;
        }
    }
}

// ==== FUSED MID: repackK(1024) | transpose_vt(512: 32x16) | transposeWo(4096: 64x64) ====
__global__ __launch_bounds__(256) void mid_fused_k(const u16* __restrict__ QKV,
                                                   const float* __restrict__ tab,
                                                   u16* __restrict__ Ko,
                                                   u16* __restrict__ VTg,
                                                   const float* __restrict__ Wo,
                                                   u16* __restrict__ WoT) {
    int b = blockIdx.x;
    int t = threadIdx.x;
    if (b < 1024) {
        int idx = b * 256 + t; // < SEQ*8*16
        int i4 = (idx & 15) * 4;
        int su = idx >> 4;
        int u = su & 7;
        int s = su >> 3;
        const float* tp = tab + (s * 64 + i4) * 2;
        f32x4 t0 = *(const f32x4*)tp;
        f32x4 t1 = *(const f32x4*)(tp + 4);
        float cv[4] = {t0[0], t0[2], t1[0], t1[2]};
        float sv[4] = {t0[1], t0[3], t1[1], t1[3]};
        const u16* base = QKV + (size_t)s * NQKV + 4096 + u * 128;
        u16* ob = Ko + ((size_t)u * SEQ + s) * 128;
        u16x4 x1 = *(const u16x4*)(base + i4);
        u16x4 x2 = *(const u16x4*)(base + 64 + i4);
        u16x4 o1, o2;
#pragma unroll
        for (int j = 0; j < 4; ++j) {
            float a = bf2f(x1[j]), b2 = bf2f(x2[j]);
            o1[j] = f2bf(a * cv[j] - b2 * sv[j]);
            o2[j] = f2bf(b2 * cv[j] + a * sv[j]);
        }
        *(u16x4*)(ob + i4) = o1;
        *(u16x4*)(ob + 64 + i4) = o2;
    } else if (b < 1536) {
        // V transpose: VT_g[hv][d][s] <- QKV[s][5120 + hv*128 + d]
        __shared__ u16 tile[64][65];
        int r = b - 1024;
        int s0 = (r % 32) * 64;
        int yy = r / 32;
        int hv = yy >> 1;
        int d0 = (yy & 1) * 64;
        const u16* src = QKV + (size_t)s0 * NQKV + 5120 + hv * 128 + d0;
#pragma unroll
        for (int it = 0; it < 4; ++it) {
            int row = it * 16 + (t >> 4);
            int col = (t & 15) * 4;
            u16x4 v = *(const u16x4*)&src[(size_t)row * NQKV + col];
            tile[row][col] = v[0]; tile[row][col + 1] = v[1];
            tile[row][col + 2] = v[2]; tile[row][col + 3] = v[3];
        }
        __syncthreads();
        u16* dst = VTg + (size_t)hv * 128 * SEQ + (size_t)d0 * SEQ + s0;
#pragma unroll
        for (int it = 0; it < 4; ++it) {
            int orow = it * 16 + (t >> 4);
            int ocol = (t & 15) * 4;
            u16x4 v;
            v[0] = tile[ocol][orow]; v[1] = tile[ocol + 1][orow];
            v[2] = tile[ocol + 2][orow]; v[3] = tile[ocol + 3][orow];
            *(u16x4*)&dst[(size_t)orow * SEQ + ocol] = v;
        }
    } else {
        int r = b - 1536;
        transpose_cast_body(Wo, WoT, 4096, 4096, r % 64, r / 64, t);
    }
}

// ---- GEMM1 big-tile (R24, best known): C[2048,6144] = A * BT^T ----
// BM=256, BN=192, BK=64; 2 LDS buffers; 4M x 2N wave partition (64x96/wave)
__global__ __launch_bounds__(512, 2) void gemm1_big_k(const u16* __restrict__ A,
                                                      const u16* __restrict__ BT,
                                                      u16* __restrict__ C) {
    constexpr int K = 4096, N = 6144;
    constexpr int SBUF = 57344;
    __shared__ alignas(16) char lds[2 * SBUF];

    int t = threadIdx.x;
    int lane = t & 63, w = t >> 6;
    int wr = w >> 1, wc = w & 1;          // 4M x 2N
    int l15 = lane & 15, l4 = lane >> 4;

    int wg = blockIdx.x;
    int xcd = wg & 7, j = wg >> 3;
    int bm = ((xcd >> 2) << 2) + (j >> 3);
    int bn = ((xcd & 3) << 3) + (j & 7);

    const u16* Ab = A + (size_t)bm * 256 * K;
    const u16* Bb = BT + (size_t)bn * 192 * K;

    const u16* ga[4]; int da[4];
#pragma unroll
    for (int i = 0; i < 4; ++i) {
        int c = t + i * 512;
        int row = c >> 3;
        int ch = (c & 7) ^ (row & 7);
        ga[i] = Ab + (size_t)row * K + ch * 8;
        da[i] = c * 16;
    }
    const u16* gb[3]; int db[3];
#pragma unroll
    for (int i = 0; i < 3; ++i) {
        int c = t + i * 512;
        int row = c >> 3;
        int ch = (c & 7) ^ (row & 7);
        gb[i] = Bb + (size_t)row * K + ch * 8;
        db[i] = 32768 + c * 16;
    }

    auto stage = [&](int kt) {
        char* L = lds + (kt & 1) * SBUF;
        int ko = kt * 64;
#pragma unroll
        for (int i = 0; i < 4; ++i) gload16(ga[i] + ko, L + da[i]);
#pragma unroll
        for (int i = 0; i < 3; ++i) gload16(gb[i] + ko, L + db[i]);
    };

    f32x4 acc[4][6];
#pragma unroll
    for (int i = 0; i < 4; ++i)
#pragma unroll
        for (int j2 = 0; j2 < 6; ++j2) acc[i][j2] = f32x4{0.f, 0.f, 0.f, 0.f};

    int arow[4];
#pragma unroll
    for (int fm = 0; fm < 4; ++fm) arow[fm] = wr * 64 + fm * 16 + l15;
    int brow[6];
#pragma unroll
    for (int fn = 0; fn < 6; ++fn) brow[fn] = wc * 96 + fn * 16 + l15;

    stage(0);
    gatebar(0);

    for (int kt = 0; kt < 64; ++kt) {
        const u16* L = (const u16*)(lds + (kt & 1) * SBUF);
        if (kt + 1 < 64) stage(kt + 1);
        bf16x8 bf[6][2];
#pragma unroll
        for (int fn = 0; fn < 6; ++fn)
#pragma unroll
            for (int kk = 0; kk < 2; ++kk) {
                int ch = (kk * 4 + l4) ^ (brow[fn] & 7);
                bf[fn][kk] = *(const bf16x8*)&L[16384 + brow[fn] * 64 + ch * 8];
            }
#pragma unroll
        for (int p = 0; p < 2; ++p) {
            bf16x8 af[2][2];
#pragma unroll
            for (int f2 = 0; f2 < 2; ++f2)
#pragma unroll
                for (int kk = 0; kk < 2; ++kk) {
                    int r = arow[p * 2 + f2];
                    int ch = (kk * 4 + l4) ^ (r & 7);
                    af[f2][kk] = *(const bf16x8*)&L[r * 64 + ch * 8];
                }
            __builtin_amdgcn_s_setprio(1);
#pragma unroll
            for (int f2 = 0; f2 < 2; ++f2)
#pragma unroll
                for (int kk = 0; kk < 2; ++kk)
#pragma unroll
                    for (int fn = 0; fn < 6; ++fn)
                        acc[p * 2 + f2][fn] = __builtin_amdgcn_mfma_f32_16x16x32_bf16(
                            af[f2][kk], bf[fn][kk], acc[p * 2 + f2][fn], 0, 0, 0);
            __builtin_amdgcn_s_setprio(0);
        }
        gatebar(0);
    }

#pragma unroll
    for (int fm = 0; fm < 4; ++fm)
#pragma unroll
        for (int fn = 0; fn < 6; ++fn)
#pragma unroll
            for (int i = 0; i < 4; ++i) {
                int row = bm * 256 + wr * 64 + fm * 16 + l4 * 4 + i;
                int col = bn * 192 + wc * 96 + fn * 16 + l15;
                C[(size_t)row * N + col] = f2bf(acc[fm][fn][i]);
            }
}

// ---- GEMM2 big-tile: out[2048,4096] = ctx[2048,4096] * WoT[4096,4096]^T ----
// 4M x 2N wave partition; 3 LDS buffers (144 KB), prefetch distance 2,
// counted vmcnt(6) gates.
__global__ __launch_bounds__(512, 2) void gemm2_big_k(const u16* __restrict__ A,
                                                      const u16* __restrict__ BT,
                                                      float* __restrict__ C) {
    constexpr int K = 4096, N = 4096;
    constexpr int SBUF = 49152;
    __shared__ alignas(16) char lds[3 * SBUF];

    int t = threadIdx.x;
    int lane = t & 63, w = t >> 6;
    int wr = w >> 1, wc = w & 1;          // 4M x 2N
    int l15 = lane & 15, l4 = lane >> 4;

    int wg = blockIdx.x;
    int xcd = wg & 7, j = wg >> 3;
    int bm = ((xcd >> 2) << 2) + (j >> 3);
    int bn = ((xcd & 3) << 3) + (j & 7);

    const u16* Ab = A + (size_t)bm * 256 * K;
    const u16* Bb = BT + (size_t)bn * 128 * K;

    const u16* ga[4]; int da[4];
#pragma unroll
    for (int i = 0; i < 4; ++i) {
        int c = t + i * 512;
        int row = c >> 3;
        int ch = (c & 7) ^ (row & 7);
        ga[i] = Ab + (size_t)row * K + ch * 8;
        da[i] = c * 16;
    }
    const u16* gb[2]; int db[2];
#pragma unroll
    for (int i = 0; i < 2; ++i) {
        int c = t + i * 512;
        int row = c >> 3;
        int ch = (c & 7) ^ (row & 7);
        gb[i] = Bb + (size_t)row * K + ch * 8;
        db[i] = 32768 + c * 16;
    }

    auto stage = [&](int kt, int b) {
        char* L = lds + b * SBUF;
        int ko = kt * 64;
#pragma unroll
        for (int i = 0; i < 4; ++i) gload16(ga[i] + ko, L + da[i]);
#pragma unroll
        for (int i = 0; i < 2; ++i) gload16(gb[i] + ko, L + db[i]);
    };

    f32x4 acc[4][4];
#pragma unroll
    for (int i = 0; i < 4; ++i)
#pragma unroll
        for (int j2 = 0; j2 < 4; ++j2) acc[i][j2] = f32x4{0.f, 0.f, 0.f, 0.f};

    int arow[4];
#pragma unroll
    for (int fm = 0; fm < 4; ++fm) arow[fm] = wr * 64 + fm * 16 + l15;
    int brow[4];
#pragma unroll
    for (int fn = 0; fn < 4; ++fn) brow[fn] = wc * 64 + fn * 16 + l15;

    stage(0, 0);
    stage(1, 1);
    gatebar(6);

    int b = 0;
    int b2 = 2;
    for (int kt = 0; kt < 64; ++kt) {
        const u16* L = (const u16*)(lds + b * SBUF);
        bool pf = (kt + 2 < 64);
        if (pf) stage(kt + 2, b2);
        bf16x8 bf[4][2];
#pragma unroll
        for (int fn = 0; fn < 4; ++fn)
#pragma unroll
            for (int kk = 0; kk < 2; ++kk) {
                int ch = (kk * 4 + l4) ^ (brow[fn] & 7);
                bf[fn][kk] = *(const bf16x8*)&L[16384 + brow[fn] * 64 + ch * 8];
            }
#pragma unroll
        for (int p = 0; p < 2; ++p) {
            bf16x8 af[2][2];
#pragma unroll
            for (int f2 = 0; f2 < 2; ++f2)
#pragma unroll
                for (int kk = 0; kk < 2; ++kk) {
                    int r = arow[p * 2 + f2];
                    int ch = (kk * 4 + l4) ^ (r & 7);
                    af[f2][kk] = *(const bf16x8*)&L[r * 64 + ch * 8];
                }
            __builtin_amdgcn_s_setprio(1);
#pragma unroll
            for (int f2 = 0; f2 < 2; ++f2)
#pragma unroll
                for (int kk = 0; kk < 2; ++kk)
#pragma unroll
                    for (int fn = 0; fn < 4; ++fn)
                        acc[p * 2 + f2][fn] = __builtin_amdgcn_mfma_f32_16x16x32_bf16(
                            af[f2][kk], bf[fn][kk], acc[p * 2 + f2][fn], 0, 0, 0);
            __builtin_amdgcn_s_setprio(0);
        }
        if (kt < 63) gatebar(pf ? 6 : 0);
        b = (b == 2) ? 0 : b + 1;
        b2 = (b2 == 2) ? 0 : b2 + 1;
    }

#pragma unroll
    for (int fm = 0; fm < 4; ++fm)
#pragma unroll
        for (int fn = 0; fn < 4; ++fn)
#pragma unroll
            for (int i = 0; i < 4; ++i) {
                int row = bm * 256 + wr * 64 + fm * 16 + l4 * 4 + i;
                int col = bn * 128 + wc * 64 + fn * 16 + l15;
                C[(size_t)row * N + col] = acc[fm][fn][i];
            }
}

// ------- causal GQA flash attention: KVBLK=128, 512 threads / 8 waves /
// ------- 128-row q-blocks, paired {bx, 15-bx}; Q direct from QKV with
// ------- in-register RoPE; softmax scale FOLDED INTO Q at load -------
__global__ __launch_bounds__(512) void attn_k(const u16* __restrict__ QKVg,
                                              const u16* __restrict__ Kg,
                                              const u16* __restrict__ VTg,
                                              const float* __restrict__ tab,
                                              u16* __restrict__ ctx) {
    constexpr float SCL2 = 0.08838834764831845f * 1.44269504088896340736f; // 1/sqrt(128)*log2e
    constexpr float THR = 11.5f;
    __shared__ alignas(16) u16 Klds[2][128 * 128];  // 2 x 32 KB
    __shared__ alignas(16) u16 VTl[2][128 * 128];   // 2 x 32 KB
    __shared__ alignas(16) u16 Plds[8 * 16 * 72];   // 18 KB, per-wave P

    int t = threadIdx.x;
    int lane = t & 63, w = t >> 6;       // 8 waves
    int l15 = lane & 15, l4 = lane >> 4;
    int bx = blockIdx.x;                 // 0..7
    int h = blockIdx.y, hkv = h >> 2;
    const u16* Kh = Kg + (size_t)hkv * SEQ * 128;
    const u16* Vh = VTg + (size_t)hkv * 128 * SEQ;  // V^T: [128][SEQ]
    u16* Pw = &Plds[w * 1152];

    int kr[4], kchs[4];
#pragma unroll
    for (int i2 = 0; i2 < 4; ++i2) {
        int c = t + i2 * 512;
        kr[i2] = c >> 4;
        kchs[i2] = (c & 15) ^ (kr[i2] & 7);
    }
    int vd[4], vchs[4];
#pragma unroll
    for (int i2 = 0; i2 < 4; ++i2) {
        int c = t + i2 * 512;
        vd[i2] = c >> 4;
        vchs[i2] = (c & 15) ^ (vd[i2] & 7);
    }

    int q0 = bx * 128;        // member A; member B = (15-bx)*128
    int ntA = bx + 1;         // A tiles (128-kv); B has 16-bx; total 17

    bf16x8 qf[4];
    f32x4 o[8];
    float m_i[4], l_i[4];

    auto kvbase = [&](int tt) { return (tt < ntA ? tt : tt - ntA) << 7; };
    auto load_q = [&]() {
        int s = q0 + w * 16 + l15;
        const u16* Qh = QKVg + (size_t)s * NQKV + h * 128;
        bf16x8 raw[4];
#pragma unroll
        for (int ks = 0; ks < 4; ++ks) raw[ks] = *(const bf16x8*)(Qh + ks * 32 + l4 * 8);
        const float* tp0 = tab + ((size_t)s * 64 + l4 * 8) * 2;
        const float* tp1 = tp0 + 64;
        float c0[8], s0[8], c1[8], s1[8];
#pragma unroll
        for (int v4 = 0; v4 < 4; ++v4) {
            f32x4 a = *(const f32x4*)(tp0 + v4 * 4);
            c0[v4 * 2] = a[0]; s0[v4 * 2] = a[1];
            c0[v4 * 2 + 1] = a[2]; s0[v4 * 2 + 1] = a[3];
            f32x4 b2 = *(const f32x4*)(tp1 + v4 * 4);
            c1[v4 * 2] = b2[0]; s1[v4 * 2] = b2[1];
            c1[v4 * 2 + 1] = b2[2]; s1[v4 * 2 + 1] = b2[3];
        }
        const u16* r0 = (const u16*)&raw[0];
        const u16* r1 = (const u16*)&raw[1];
        const u16* r2 = (const u16*)&raw[2];
        const u16* r3 = (const u16*)&raw[3];
        u16* q0p = (u16*)&qf[0];
        u16* q1p = (u16*)&qf[1];
        u16* q2p = (u16*)&qf[2];
        u16* q3p = (u16*)&qf[3];
#pragma unroll
        for (int j = 0; j < 8; ++j) {
            float x0 = bf2f(r0[j]), x1 = bf2f(r1[j]);
            float x2 = bf2f(r2[j]), x3 = bf2f(r3[j]);
            q0p[j] = f2bf((x0 * c0[j] - x2 * s0[j]) * SCL2);
            q2p[j] = f2bf((x2 * c0[j] + x0 * s0[j]) * SCL2);
            q1p[j] = f2bf((x1 * c1[j] - x3 * s1[j]) * SCL2);
            q3p[j] = f2bf((x3 * c1[j] + x1 * s1[j]) * SCL2);
        }
    };
    auto reset_acc = [&]() {
#pragma unroll
        for (int nf = 0; nf < 8; ++nf) o[nf] = f32x4{0.f, 0.f, 0.f, 0.f};
#pragma unroll
        for (int i = 0; i < 4; ++i) { m_i[i] = -3.0e38f; l_i[i] = 0.f; }
    };
    auto write_ctx = [&]() {
        float inv[4];
#pragma unroll
        for (int i = 0; i < 4; ++i) {
            float rs = l_i[i];
            rs += __shfl_xor(rs, 1);
            rs += __shfl_xor(rs, 2);
            rs += __shfl_xor(rs, 4);
            rs += __shfl_xor(rs, 8);
            inv[i] = 1.0f / rs;
        }
#pragma unroll
        for (int nf = 0; nf < 8; ++nf)
#pragma unroll
            for (int i = 0; i < 4; ++i) {
                int qrow = q0 + w * 16 + l4 * 4 + i;
                ctx[(size_t)qrow * 4096 + h * 128 + nf * 16 + l15] = f2bf(o[nf][i] * inv[i]);
            }
    };
    auto stage = [&](int tt) {
        int kv0 = kvbase(tt);
        const u16* Kt = Kh + (size_t)kv0 * 128;
        char* kb = (char*)Klds[tt & 1];
        char* vb = (char*)VTl[tt & 1];
#pragma unroll
        for (int i2 = 0; i2 < 4; ++i2)
            gload16(Kt + kr[i2] * 128 + kchs[i2] * 8, kb + (size_t)(t + i2 * 512) * 16);
#pragma unroll
        for (int i2 = 0; i2 < 4; ++i2)
            gload16(Vh + (size_t)vd[i2] * SEQ + kv0 + vchs[i2] * 8,
                    vb + (size_t)(t + i2 * 512) * 16);
    };

    load_q();
    reset_acc();
    stage(0);

    for (int tt = 0; tt < 17; ++tt) {
        __builtin_amdgcn_s_barrier();
        __builtin_amdgcn_sched_barrier(0);
        bool nxt = (tt + 1 < 17);
        if (nxt) stage(tt + 1);
        gatebar(nxt ? 8 : 0);
        if (tt == ntA) {
            write_ctx();
            q0 = (15 - bx) * 128;
            load_q();
            reset_acc();
        }

        int b = tt & 1;
        int kv0 = kvbase(tt);
        const u16* KL = Klds[b];
        const u16* VL = VTl[b];

        f32x4 sa[8];
#pragma unroll
        for (int cg = 0; cg < 8; ++cg) {
            sa[cg] = f32x4{0.f, 0.f, 0.f, 0.f};
            int row = cg * 16 + l15;
#pragma unroll
            for (int ks = 0; ks < 4; ++ks) {
                int chs = (ks * 4 + l4) ^ (row & 7);
                bf16x8 kf = *(const bf16x8*)&KL[row * 128 + chs * 8];
                sa[cg] = __builtin_amdgcn_mfma_f32_16x16x32_bf16(qf[ks], kf, sa[cg], 0, 0, 0);
            }
        }
        // (scale already folded into Q)
        if (kv0 + 127 > q0 + w * 16) {
#pragma unroll
            for (int cg = 0; cg < 8; ++cg) {
                int col = kv0 + cg * 16 + l15;
#pragma unroll
                for (int i = 0; i < 4; ++i) {
                    int qrow = q0 + w * 16 + l4 * 4 + i;
                    if (col > qrow) sa[cg][i] = -3.0e38f;
                }
            }
        }
        float lmx[4];
#pragma unroll
        for (int i = 0; i < 4; ++i) {
            float a0 = fmaxf(fmaxf(sa[0][i], sa[1][i]), fmaxf(sa[2][i], sa[3][i]));
            float a1 = fmaxf(fmaxf(sa[4][i], sa[5][i]), fmaxf(sa[6][i], sa[7][i]));
            lmx[i] = fmaxf(a0, a1);
        }
        bool defer = __all((lmx[0] <= m_i[0] + THR) & (lmx[1] <= m_i[1] + THR) &
                           (lmx[2] <= m_i[2] + THR) & (lmx[3] <= m_i[3] + THR));
        if (!defer) {
            float corr[4];
#pragma unroll
            for (int i = 0; i < 4; ++i) {
                float m0 = lmx[i];
                m0 = fmaxf(m0, __shfl_xor(m0, 1));
                m0 = fmaxf(m0, __shfl_xor(m0, 2));
                m0 = fmaxf(m0, __shfl_xor(m0, 4));
                m0 = fmaxf(m0, __shfl_xor(m0, 8));
                float mnew = fmaxf(m_i[i], m0);
                corr[i] = __builtin_amdgcn_exp2f(m_i[i] - mnew);
                m_i[i] = mnew;
                l_i[i] *= corr[i];
            }
#pragma unroll
            for (int nf = 0; nf < 8; ++nf) {
                o[nf][0] *= corr[0]; o[nf][1] *= corr[1];
                o[nf][2] *= corr[2]; o[nf][3] *= corr[3];
            }
        }
#pragma unroll
        for (int hf = 0; hf < 2; ++hf) {
#pragma unroll
            for (int i = 0; i < 4; ++i) {
                int prow = l4 * 4 + i;
                int sw = (prow >> 1) & 3;
                float rs = 0.f;
#pragma unroll
                for (int cg = 0; cg < 4; ++cg) {
                    float p = __builtin_amdgcn_exp2f(sa[hf * 4 + cg][i] - m_i[i]);
                    rs += p;
                    int ch = cg * 2 + (l15 >> 3);
                    Pw[prow * 72 + ((ch ^ sw) << 3) + (l15 & 7)] = f2bf(p);
                }
                l_i[i] += rs;
            }
            asm volatile("s_waitcnt lgkmcnt(0)" ::: "memory");
            __builtin_amdgcn_sched_barrier(0);
#pragma unroll
            for (int kst = 0; kst < 2; ++kst) {
                int pchs = (kst * 4 + l4) ^ ((l15 >> 1) & 3);
                bf16x8 pf = *(const bf16x8*)&Pw[l15 * 72 + pchs * 8];
                int kst2 = hf * 2 + kst;
#pragma unroll
                for (int nf = 0; nf < 8; ++nf) {
                    int d = nf * 16 + l15;
                    int vch = (kst2 * 4 + l4) ^ (d & 7);
                    bf16x8 vf = *(const bf16x8*)&VL[d * 128 + vch * 8];
                    o[nf] = __builtin_amdgcn_mfma_f32_16x16x32_bf16(pf, vf, o[nf], 0, 0, 0);
                }
            }
        }
    }
    write_ctx();
}

extern "C" void kernel_launch(void* const* d_in, const int* in_sizes, int n_in,
                              void* d_out, int out_size, void* d_ws, size_t ws_size,
                              hipStream_t stream) {
    const float* hidden = (const float*)d_in[0];   // fp32 (per reference dtype)
    // d_in[1] = sequence_mask (unused by reference math: all-ones + causal)
    const float* Wqkv = (const float*)d_in[2];     // fp32
    const float* Wo = (const float*)d_in[3];       // fp32
    float* out = (float*)d_out;                    // fp32 output
    char* ws = (char*)d_ws;

    // ws layout (bytes), liveness audited (QKV stays live through attn as Q source):
    //   QKV     [0,        25165824)  gemm1 -> attn(Q) / mid(K,V)
    //   WqkvT   [25165824, 75497472)  pre -> gemm1 (dead after gemm1)
    //   Kb      [25165824, 29360128)  mid -> attn           (in dead WqkvT)
    //   VTg     [29360128, 33554432)  mid -> attn           (in dead WqkvT)
    //   WoT     [34603008, 68157440)  mid -> gemm2          (in dead WqkvT)
    //   ctx     [68157440, 84934656)  attn -> gemm2         (dead WqkvT + dead hiddenB)
    //   hiddenB [75497472, 92274688)  pre -> gemm1 (dead after gemm1)
    //   tab     [92274688, 93323264)  pre -> mid+attn (disjoint from all live regions)
    u16* QKV     = (u16*)(ws + 0);
    u16* WqkvT   = (u16*)(ws + 25165824);
    u16* Kb      = (u16*)(ws + 25165824);
    u16* VTg     = (u16*)(ws + 29360128);
    u16* WoT     = (u16*)(ws + 34603008);
    u16* ctx     = (u16*)(ws + 68157440);
    u16* hiddenB = (u16*)(ws + 75497472);
    float* tab   = (float*)(ws + 92274688);  // disjoint from everything live

    pre_fused_k<<<14848, 256, 0, stream>>>(hidden, hiddenB, Wqkv, WqkvT, tab);
    gemm1_big_k<<<512, 512, 0, stream>>>(hiddenB, WqkvT, QKV);
    mid_fused_k<<<5632, 256, 0, stream>>>(QKV, tab, Kb, VTg, Wo, WoT);
    attn_k<<<dim3(8, 32), 512, 0, stream>>>(QKV, Kb, VTg, tab, ctx);
    gemm2_big_k<<<256, 512, 0, stream>>>(ctx, WoT, out);
}

// Round 27
// 284.092 us; speedup vs baseline: 1.2888x; 1.2888x over previous
//
#include <hip/hip_runtime.h>

typedef unsigned short u16;
typedef __bf16 bf16x8 __attribute__((ext_vector_type(8)));
typedef float f32x4 __attribute__((ext_vector_type(4)));
typedef u16 u16x4 __attribute__((ext_vector_type(4)));

constexpr int SEQ = 2048;
constexpr int NQKV = 6144; // (32 + 2*8) * 128

__device__ __forceinline__ float bf2f(u16 x) {
    unsigned int u = ((unsigned int)x) << 16;
    return __builtin_bit_cast(float, u);
}
__device__ __forceinline__ u16 f2bf(float f) {
    unsigned int u = __builtin_bit_cast(unsigned int, f);
    u += 0x7FFF + ((u >> 16) & 1);
    return (u16)(u >> 16);
}

__device__ __forceinline__ void gload16(const void* g, void* l) {
    void* gg = const_cast<void*>(g);
    __builtin_amdgcn_global_load_lds(
        (__attribute__((address_space(1))) void*)gg,
        (__attribute__((address_space(3))) void*)l, 16, 0, 0);
}

// counted-vmcnt gate + raw barrier
__device__ __forceinline__ void gatebar(int G) {
    if (G == 8) asm volatile("s_waitcnt vmcnt(8)" ::: "memory");
    else if (G == 6) asm volatile("s_waitcnt vmcnt(6)" ::: "memory");
    else if (G == 4) asm volatile("s_waitcnt vmcnt(4)" ::: "memory");
    else asm volatile("s_waitcnt vmcnt(0)" ::: "memory");
    __builtin_amdgcn_sched_barrier(0);
    __builtin_amdgcn_s_barrier();
    __builtin_amdgcn_sched_barrier(0);
}

// ---- fp32 transpose+cast body (R x C fp32 -> C x R bf16), 64x64 tile ----
__device__ __forceinline__ void transpose_cast_body(const float* __restrict__ src,
                                                    u16* __restrict__ dst, int R, int C,
                                                    int bx, int by, int t) {
    __shared__ u16 tile[64][65];
    int r0 = by * 64, c0 = bx * 64;
#pragma unroll
    for (int it = 0; it < 4; ++it) {
        int row = it * 16 + (t >> 4);
        int col = (t & 15) * 4;
        f32x4 v = *(const f32x4*)&src[(size_t)(r0 + row) * C + c0 + col];
        tile[row][col] = f2bf(v[0]); tile[row][col + 1] = f2bf(v[1]);
        tile[row][col + 2] = f2bf(v[2]); tile[row][col + 3] = f2bf(v[3]);
    }
    __syncthreads();
#pragma unroll
    for (int it = 0; it < 4; ++it) {
        int orow = it * 16 + (t >> 4);
        int ocol = (t & 15) * 4;
        u16x4 v;
        v[0] = tile[ocol][orow]; v[1] = tile[ocol + 1][orow];
        v[2] = tile[ocol + 2][orow]; v[3] = tile[ocol + 3][orow];
        *(u16x4*)&dst[(size_t)(c0 + orow) * R + r0 + ocol] = v;
    }
}

// ==== FUSED PRE: cast(8192) | transposeWqkv(6144: 96x64) | rope_table(512) ====
__global__ __launch_bounds__(256) void pre_fused_k(const float* __restrict__ hidden,
                                                   u16* __restrict__ hiddenB,
                                                   const float* __restrict__ Wqkv,
                                                   u16* __restrict__ WqkvT,
                                                   float* __restrict__ tab) {
    int b = blockIdx.x;
    int t = threadIdx.x;
    if (b < 8192) {
        int i = b * 256 + t;
        f32x4 v = *(const f32x4*)&hidden[(size_t)i * 4];
        u16x4 o;
#pragma unroll
        for (int j = 0; j < 4; ++j) o[j] = f2bf(v[j]);
        *(u16x4*)&hiddenB[(size_t)i * 4] = o;
    } else if (b < 8192 + 6144) {
        int r = b - 8192;
        transpose_cast_body(Wqkv, WqkvT, 4096, 6144, r % 96, r / 96, t);
    } else {
        int idx = (b - 14336) * 256 + t;
        if (idx < SEQ * 64) {
            int s = idx >> 6;
            int i = idx & 63;
            float invf = expf(-(float)i * (float)(1.0 / 64.0) * logf(10000.0f));
            float ang = (float)s * invf;
            float sv, cv;
            sincosf(ang, &sv, &cv);
            tab[idx * 2] = cv;
            tab[idx * 2 + 1] = sv;
        }
    }
}

// ==== FUSED MID: repackK(1024) | transpose_vt(512: 32x16) | transposeWo(4096: 64x64) ====
__global__ __launch_bounds__(256) void mid_fused_k(const u16* __restrict__ QKV,
                                                   const float* __restrict__ tab,
                                                   u16* __restrict__ Ko,
                                                   u16* __restrict__ VTg,
                                                   const float* __restrict__ Wo,
                                                   u16* __restrict__ WoT) {
    int b = blockIdx.x;
    int t = threadIdx.x;
    if (b < 1024) {
        int idx = b * 256 + t; // < SEQ*8*16
        int i4 = (idx & 15) * 4;
        int su = idx >> 4;
        int u = su & 7;
        int s = su >> 3;
        const float* tp = tab + (s * 64 + i4) * 2;
        f32x4 t0 = *(const f32x4*)tp;
        f32x4 t1 = *(const f32x4*)(tp + 4);
        float cv[4] = {t0[0], t0[2], t1[0], t1[2]};
        float sv[4] = {t0[1], t0[3], t1[1], t1[3]};
        const u16* base = QKV + (size_t)s * NQKV + 4096 + u * 128;
        u16* ob = Ko + ((size_t)u * SEQ + s) * 128;
        u16x4 x1 = *(const u16x4*)(base + i4);
        u16x4 x2 = *(const u16x4*)(base + 64 + i4);
        u16x4 o1, o2;
#pragma unroll
        for (int j = 0; j < 4; ++j) {
            float a = bf2f(x1[j]), b2 = bf2f(x2[j]);
            o1[j] = f2bf(a * cv[j] - b2 * sv[j]);
            o2[j] = f2bf(b2 * cv[j] + a * sv[j]);
        }
        *(u16x4*)(ob + i4) = o1;
        *(u16x4*)(ob + 64 + i4) = o2;
    } else if (b < 1536) {
        // V transpose: VT_g[hv][d][s] <- QKV[s][5120 + hv*128 + d]
        __shared__ u16 tile[64][65];
        int r = b - 1024;
        int s0 = (r % 32) * 64;
        int yy = r / 32;
        int hv = yy >> 1;
        int d0 = (yy & 1) * 64;
        const u16* src = QKV + (size_t)s0 * NQKV + 5120 + hv * 128 + d0;
#pragma unroll
        for (int it = 0; it < 4; ++it) {
            int row = it * 16 + (t >> 4);
            int col = (t & 15) * 4;
            u16x4 v = *(const u16x4*)&src[(size_t)row * NQKV + col];
            tile[row][col] = v[0]; tile[row][col + 1] = v[1];
            tile[row][col + 2] = v[2]; tile[row][col + 3] = v[3];
        }
        __syncthreads();
        u16* dst = VTg + (size_t)hv * 128 * SEQ + (size_t)d0 * SEQ + s0;
#pragma unroll
        for (int it = 0; it < 4; ++it) {
            int orow = it * 16 + (t >> 4);
            int ocol = (t & 15) * 4;
            u16x4 v;
            v[0] = tile[ocol][orow]; v[1] = tile[ocol + 1][orow];
            v[2] = tile[ocol + 2][orow]; v[3] = tile[ocol + 3][orow];
            *(u16x4*)&dst[(size_t)orow * SEQ + ocol] = v;
        }
    } else {
        int r = b - 1536;
        transpose_cast_body(Wo, WoT, 4096, 4096, r % 64, r / 64, t);
    }
}

// ---- GEMM1 big-tile (R24, best known): C[2048,6144] = A * BT^T ----
// BM=256, BN=192, BK=64; 2 LDS buffers; 4M x 2N wave partition (64x96/wave)
// GRID MUST BE 256 BLOCKS (nbm=8 x nbn=32 / 8 per XCD rectangle).
__global__ __launch_bounds__(512, 2) void gemm1_big_k(const u16* __restrict__ A,
                                                      const u16* __restrict__ BT,
                                                      u16* __restrict__ C) {
    constexpr int K = 4096, N = 6144;
    constexpr int SBUF = 57344;
    __shared__ alignas(16) char lds[2 * SBUF];

    int t = threadIdx.x;
    int lane = t & 63, w = t >> 6;
    int wr = w >> 1, wc = w & 1;          // 4M x 2N
    int l15 = lane & 15, l4 = lane >> 4;

    int wg = blockIdx.x;
    int xcd = wg & 7, j = wg >> 3;        // j in 0..31
    int bm = ((xcd >> 2) << 2) + (j >> 3);
    int bn = ((xcd & 3) << 3) + (j & 7);

    const u16* Ab = A + (size_t)bm * 256 * K;
    const u16* Bb = BT + (size_t)bn * 192 * K;

    const u16* ga[4]; int da[4];
#pragma unroll
    for (int i = 0; i < 4; ++i) {
        int c = t + i * 512;
        int row = c >> 3;
        int ch = (c & 7) ^ (row & 7);
        ga[i] = Ab + (size_t)row * K + ch * 8;
        da[i] = c * 16;
    }
    const u16* gb[3]; int db[3];
#pragma unroll
    for (int i = 0; i < 3; ++i) {
        int c = t + i * 512;
        int row = c >> 3;
        int ch = (c & 7) ^ (row & 7);
        gb[i] = Bb + (size_t)row * K + ch * 8;
        db[i] = 32768 + c * 16;
    }

    auto stage = [&](int kt) {
        char* L = lds + (kt & 1) * SBUF;
        int ko = kt * 64;
#pragma unroll
        for (int i = 0; i < 4; ++i) gload16(ga[i] + ko, L + da[i]);
#pragma unroll
        for (int i = 0; i < 3; ++i) gload16(gb[i] + ko, L + db[i]);
    };

    f32x4 acc[4][6];
#pragma unroll
    for (int i = 0; i < 4; ++i)
#pragma unroll
        for (int j2 = 0; j2 < 6; ++j2) acc[i][j2] = f32x4{0.f, 0.f, 0.f, 0.f};

    int arow[4];
#pragma unroll
    for (int fm = 0; fm < 4; ++fm) arow[fm] = wr * 64 + fm * 16 + l15;
    int brow[6];
#pragma unroll
    for (int fn = 0; fn < 6; ++fn) brow[fn] = wc * 96 + fn * 16 + l15;

    stage(0);
    gatebar(0);

    for (int kt = 0; kt < 64; ++kt) {
        const u16* L = (const u16*)(lds + (kt & 1) * SBUF);
        if (kt + 1 < 64) stage(kt + 1);
        bf16x8 bf[6][2];
#pragma unroll
        for (int fn = 0; fn < 6; ++fn)
#pragma unroll
            for (int kk = 0; kk < 2; ++kk) {
                int ch = (kk * 4 + l4) ^ (brow[fn] & 7);
                bf[fn][kk] = *(const bf16x8*)&L[16384 + brow[fn] * 64 + ch * 8];
            }
#pragma unroll
        for (int p = 0; p < 2; ++p) {
            bf16x8 af[2][2];
#pragma unroll
            for (int f2 = 0; f2 < 2; ++f2)
#pragma unroll
                for (int kk = 0; kk < 2; ++kk) {
                    int r = arow[p * 2 + f2];
                    int ch = (kk * 4 + l4) ^ (r & 7);
                    af[f2][kk] = *(const bf16x8*)&L[r * 64 + ch * 8];
                }
            __builtin_amdgcn_s_setprio(1);
#pragma unroll
            for (int f2 = 0; f2 < 2; ++f2)
#pragma unroll
                for (int kk = 0; kk < 2; ++kk)
#pragma unroll
                    for (int fn = 0; fn < 6; ++fn)
                        acc[p * 2 + f2][fn] = __builtin_amdgcn_mfma_f32_16x16x32_bf16(
                            af[f2][kk], bf[fn][kk], acc[p * 2 + f2][fn], 0, 0, 0);
            __builtin_amdgcn_s_setprio(0);
        }
        gatebar(0);
    }

#pragma unroll
    for (int fm = 0; fm < 4; ++fm)
#pragma unroll
        for (int fn = 0; fn < 6; ++fn)
#pragma unroll
            for (int i = 0; i < 4; ++i) {
                int row = bm * 256 + wr * 64 + fm * 16 + l4 * 4 + i;
                int col = bn * 192 + wc * 96 + fn * 16 + l15;
                C[(size_t)row * N + col] = f2bf(acc[fm][fn][i]);
            }
}

// ---- GEMM2 big-tile: out[2048,4096] = ctx[2048,4096] * WoT[4096,4096]^T ----
// 4M x 2N wave partition; 3 LDS buffers (144 KB), prefetch distance 2,
// counted vmcnt(6) gates.
__global__ __launch_bounds__(512, 2) void gemm2_big_k(const u16* __restrict__ A,
                                                      const u16* __restrict__ BT,
                                                      float* __restrict__ C) {
    constexpr int K = 4096, N = 4096;
    constexpr int SBUF = 49152;
    __shared__ alignas(16) char lds[3 * SBUF];

    int t = threadIdx.x;
    int lane = t & 63, w = t >> 6;
    int wr = w >> 1, wc = w & 1;          // 4M x 2N
    int l15 = lane & 15, l4 = lane >> 4;

    int wg = blockIdx.x;
    int xcd = wg & 7, j = wg >> 3;
    int bm = ((xcd >> 2) << 2) + (j >> 3);
    int bn = ((xcd & 3) << 3) + (j & 7);

    const u16* Ab = A + (size_t)bm * 256 * K;
    const u16* Bb = BT + (size_t)bn * 128 * K;

    const u16* ga[4]; int da[4];
#pragma unroll
    for (int i = 0; i < 4; ++i) {
        int c = t + i * 512;
        int row = c >> 3;
        int ch = (c & 7) ^ (row & 7);
        ga[i] = Ab + (size_t)row * K + ch * 8;
        da[i] = c * 16;
    }
    const u16* gb[2]; int db[2];
#pragma unroll
    for (int i = 0; i < 2; ++i) {
        int c = t + i * 512;
        int row = c >> 3;
        int ch = (c & 7) ^ (row & 7);
        gb[i] = Bb + (size_t)row * K + ch * 8;
        db[i] = 32768 + c * 16;
    }

    auto stage = [&](int kt, int b) {
        char* L = lds + b * SBUF;
        int ko = kt * 64;
#pragma unroll
        for (int i = 0; i < 4; ++i) gload16(ga[i] + ko, L + da[i]);
#pragma unroll
        for (int i = 0; i < 2; ++i) gload16(gb[i] + ko, L + db[i]);
    };

    f32x4 acc[4][4];
#pragma unroll
    for (int i = 0; i < 4; ++i)
#pragma unroll
        for (int j2 = 0; j2 < 4; ++j2) acc[i][j2] = f32x4{0.f, 0.f, 0.f, 0.f};

    int arow[4];
#pragma unroll
    for (int fm = 0; fm < 4; ++fm) arow[fm] = wr * 64 + fm * 16 + l15;
    int brow[4];
#pragma unroll
    for (int fn = 0; fn < 4; ++fn) brow[fn] = wc * 64 + fn * 16 + l15;

    stage(0, 0);
    stage(1, 1);
    gatebar(6);

    int b = 0;
    int b2 = 2;
    for (int kt = 0; kt < 64; ++kt) {
        const u16* L = (const u16*)(lds + b * SBUF);
        bool pf = (kt + 2 < 64);
        if (pf) stage(kt + 2, b2);
        bf16x8 bf[4][2];
#pragma unroll
        for (int fn = 0; fn < 4; ++fn)
#pragma unroll
            for (int kk = 0; kk < 2; ++kk) {
                int ch = (kk * 4 + l4) ^ (brow[fn] & 7);
                bf[fn][kk] = *(const bf16x8*)&L[16384 + brow[fn] * 64 + ch * 8];
            }
#pragma unroll
        for (int p = 0; p < 2; ++p) {
            bf16x8 af[2][2];
#pragma unroll
            for (int f2 = 0; f2 < 2; ++f2)
#pragma unroll
                for (int kk = 0; kk < 2; ++kk) {
                    int r = arow[p * 2 + f2];
                    int ch = (kk * 4 + l4) ^ (r & 7);
                    af[f2][kk] = *(const bf16x8*)&L[r * 64 + ch * 8];
                }
            __builtin_amdgcn_s_setprio(1);
#pragma unroll
            for (int f2 = 0; f2 < 2; ++f2)
#pragma unroll
                for (int kk = 0; kk < 2; ++kk)
#pragma unroll
                    for (int fn = 0; fn < 4; ++fn)
                        acc[p * 2 + f2][fn] = __builtin_amdgcn_mfma_f32_16x16x32_bf16(
                            af[f2][kk], bf[fn][kk], acc[p * 2 + f2][fn], 0, 0, 0);
            __builtin_amdgcn_s_setprio(0);
        }
        if (kt < 63) gatebar(pf ? 6 : 0);
        b = (b == 2) ? 0 : b + 1;
        b2 = (b2 == 2) ? 0 : b2 + 1;
    }

#pragma unroll
    for (int fm = 0; fm < 4; ++fm)
#pragma unroll
        for (int fn = 0; fn < 4; ++fn)
#pragma unroll
            for (int i = 0; i < 4; ++i) {
                int row = bm * 256 + wr * 64 + fm * 16 + l4 * 4 + i;
                int col = bn * 128 + wc * 64 + fn * 16 + l15;
                C[(size_t)row * N + col] = acc[fm][fn][i];
            }
}

// ------- causal GQA flash attention: KVBLK=128, 512 threads / 8 waves /
// ------- 128-row q-blocks, paired {bx, 15-bx}; Q direct from QKV with
// ------- in-register RoPE; softmax scale FOLDED INTO Q at load -------
__global__ __launch_bounds__(512) void attn_k(const u16* __restrict__ QKVg,
                                              const u16* __restrict__ Kg,
                                              const u16* __restrict__ VTg,
                                              const float* __restrict__ tab,
                                              u16* __restrict__ ctx) {
    constexpr float SCL2 = 0.08838834764831845f * 1.44269504088896340736f; // 1/sqrt(128)*log2e
    constexpr float THR = 11.5f;
    __shared__ alignas(16) u16 Klds[2][128 * 128];  // 2 x 32 KB
    __shared__ alignas(16) u16 VTl[2][128 * 128];   // 2 x 32 KB
    __shared__ alignas(16) u16 Plds[8 * 16 * 72];   // 18 KB, per-wave P

    int t = threadIdx.x;
    int lane = t & 63, w = t >> 6;       // 8 waves
    int l15 = lane & 15, l4 = lane >> 4;
    int bx = blockIdx.x;                 // 0..7
    int h = blockIdx.y, hkv = h >> 2;
    const u16* Kh = Kg + (size_t)hkv * SEQ * 128;
    const u16* Vh = VTg + (size_t)hkv * 128 * SEQ;  // V^T: [128][SEQ]
    u16* Pw = &Plds[w * 1152];

    int kr[4], kchs[4];
#pragma unroll
    for (int i2 = 0; i2 < 4; ++i2) {
        int c = t + i2 * 512;
        kr[i2] = c >> 4;
        kchs[i2] = (c & 15) ^ (kr[i2] & 7);
    }
    int vd[4], vchs[4];
#pragma unroll
    for (int i2 = 0; i2 < 4; ++i2) {
        int c = t + i2 * 512;
        vd[i2] = c >> 4;
        vchs[i2] = (c & 15) ^ (vd[i2] & 7);
    }

    int q0 = bx * 128;        // member A; member B = (15-bx)*128
    int ntA = bx + 1;         // A tiles (128-kv); B has 16-bx; total 17

    bf16x8 qf[4];
    f32x4 o[8];
    float m_i[4], l_i[4];

    auto kvbase = [&](int tt) { return (tt < ntA ? tt : tt - ntA) << 7; };
    auto load_q = [&]() {
        int s = q0 + w * 16 + l15;
        const u16* Qh = QKVg + (size_t)s * NQKV + h * 128;
        bf16x8 raw[4];
#pragma unroll
        for (int ks = 0; ks < 4; ++ks) raw[ks] = *(const bf16x8*)(Qh + ks * 32 + l4 * 8);
        const float* tp0 = tab + ((size_t)s * 64 + l4 * 8) * 2;
        const float* tp1 = tp0 + 64;
        float c0[8], s0[8], c1[8], s1[8];
#pragma unroll
        for (int v4 = 0; v4 < 4; ++v4) {
            f32x4 a = *(const f32x4*)(tp0 + v4 * 4);
            c0[v4 * 2] = a[0]; s0[v4 * 2] = a[1];
            c0[v4 * 2 + 1] = a[2]; s0[v4 * 2 + 1] = a[3];
            f32x4 b2 = *(const f32x4*)(tp1 + v4 * 4);
            c1[v4 * 2] = b2[0]; s1[v4 * 2] = b2[1];
            c1[v4 * 2 + 1] = b2[2]; s1[v4 * 2 + 1] = b2[3];
        }
        const u16* r0 = (const u16*)&raw[0];
        const u16* r1 = (const u16*)&raw[1];
        const u16* r2 = (const u16*)&raw[2];
        const u16* r3 = (const u16*)&raw[3];
        u16* q0p = (u16*)&qf[0];
        u16* q1p = (u16*)&qf[1];
        u16* q2p = (u16*)&qf[2];
        u16* q3p = (u16*)&qf[3];
#pragma unroll
        for (int j = 0; j < 8; ++j) {
            float x0 = bf2f(r0[j]), x1 = bf2f(r1[j]);
            float x2 = bf2f(r2[j]), x3 = bf2f(r3[j]);
            q0p[j] = f2bf((x0 * c0[j] - x2 * s0[j]) * SCL2);
            q2p[j] = f2bf((x2 * c0[j] + x0 * s0[j]) * SCL2);
            q1p[j] = f2bf((x1 * c1[j] - x3 * s1[j]) * SCL2);
            q3p[j] = f2bf((x3 * c1[j] + x1 * s1[j]) * SCL2);
        }
    };
    auto reset_acc = [&]() {
#pragma unroll
        for (int nf = 0; nf < 8; ++nf) o[nf] = f32x4{0.f, 0.f, 0.f, 0.f};
#pragma unroll
        for (int i = 0; i < 4; ++i) { m_i[i] = -3.0e38f; l_i[i] = 0.f; }
    };
    auto write_ctx = [&]() {
        float inv[4];
#pragma unroll
        for (int i = 0; i < 4; ++i) {
            float rs = l_i[i];
            rs += __shfl_xor(rs, 1);
            rs += __shfl_xor(rs, 2);
            rs += __shfl_xor(rs, 4);
            rs += __shfl_xor(rs, 8);
            inv[i] = 1.0f / rs;
        }
#pragma unroll
        for (int nf = 0; nf < 8; ++nf)
#pragma unroll
            for (int i = 0; i < 4; ++i) {
                int qrow = q0 + w * 16 + l4 * 4 + i;
                ctx[(size_t)qrow * 4096 + h * 128 + nf * 16 + l15] = f2bf(o[nf][i] * inv[i]);
            }
    };
    auto stage = [&](int tt) {
        int kv0 = kvbase(tt);
        const u16* Kt = Kh + (size_t)kv0 * 128;
        char* kb = (char*)Klds[tt & 1];
        char* vb = (char*)VTl[tt & 1];
#pragma unroll
        for (int i2 = 0; i2 < 4; ++i2)
            gload16(Kt + kr[i2] * 128 + kchs[i2] * 8, kb + (size_t)(t + i2 * 512) * 16);
#pragma unroll
        for (int i2 = 0; i2 < 4; ++i2)
            gload16(Vh + (size_t)vd[i2] * SEQ + kv0 + vchs[i2] * 8,
                    vb + (size_t)(t + i2 * 512) * 16);
    };

    load_q();
    reset_acc();
    stage(0);

    for (int tt = 0; tt < 17; ++tt) {
        __builtin_amdgcn_s_barrier();
        __builtin_amdgcn_sched_barrier(0);
        bool nxt = (tt + 1 < 17);
        if (nxt) stage(tt + 1);
        gatebar(nxt ? 8 : 0);
        if (tt == ntA) {
            write_ctx();
            q0 = (15 - bx) * 128;
            load_q();
            reset_acc();
        }

        int b = tt & 1;
        int kv0 = kvbase(tt);
        const u16* KL = Klds[b];
        const u16* VL = VTl[b];

        f32x4 sa[8];
#pragma unroll
        for (int cg = 0; cg < 8; ++cg) {
            sa[cg] = f32x4{0.f, 0.f, 0.f, 0.f};
            int row = cg * 16 + l15;
#pragma unroll
            for (int ks = 0; ks < 4; ++ks) {
                int chs = (ks * 4 + l4) ^ (row & 7);
                bf16x8 kf = *(const bf16x8*)&KL[row * 128 + chs * 8];
                sa[cg] = __builtin_amdgcn_mfma_f32_16x16x32_bf16(qf[ks], kf, sa[cg], 0, 0, 0);
            }
        }
        // (scale already folded into Q)
        if (kv0 + 127 > q0 + w * 16) {
#pragma unroll
            for (int cg = 0; cg < 8; ++cg) {
                int col = kv0 + cg * 16 + l15;
#pragma unroll
                for (int i = 0; i < 4; ++i) {
                    int qrow = q0 + w * 16 + l4 * 4 + i;
                    if (col > qrow) sa[cg][i] = -3.0e38f;
                }
            }
        }
        float lmx[4];
#pragma unroll
        for (int i = 0; i < 4; ++i) {
            float a0 = fmaxf(fmaxf(sa[0][i], sa[1][i]), fmaxf(sa[2][i], sa[3][i]));
            float a1 = fmaxf(fmaxf(sa[4][i], sa[5][i]), fmaxf(sa[6][i], sa[7][i]));
            lmx[i] = fmaxf(a0, a1);
        }
        bool defer = __all((lmx[0] <= m_i[0] + THR) & (lmx[1] <= m_i[1] + THR) &
                           (lmx[2] <= m_i[2] + THR) & (lmx[3] <= m_i[3] + THR));
        if (!defer) {
            float corr[4];
#pragma unroll
            for (int i = 0; i < 4; ++i) {
                float m0 = lmx[i];
                m0 = fmaxf(m0, __shfl_xor(m0, 1));
                m0 = fmaxf(m0, __shfl_xor(m0, 2));
                m0 = fmaxf(m0, __shfl_xor(m0, 4));
                m0 = fmaxf(m0, __shfl_xor(m0, 8));
                float mnew = fmaxf(m_i[i], m0);
                corr[i] = __builtin_amdgcn_exp2f(m_i[i] - mnew);
                m_i[i] = mnew;
                l_i[i] *= corr[i];
            }
#pragma unroll
            for (int nf = 0; nf < 8; ++nf) {
                o[nf][0] *= corr[0]; o[nf][1] *= corr[1];
                o[nf][2] *= corr[2]; o[nf][3] *= corr[3];
            }
        }
#pragma unroll
        for (int hf = 0; hf < 2; ++hf) {
#pragma unroll
            for (int i = 0; i < 4; ++i) {
                int prow = l4 * 4 + i;
                int sw = (prow >> 1) & 3;
                float rs = 0.f;
#pragma unroll
                for (int cg = 0; cg < 4; ++cg) {
                    float p = __builtin_amdgcn_exp2f(sa[hf * 4 + cg][i] - m_i[i]);
                    rs += p;
                    int ch = cg * 2 + (l15 >> 3);
                    Pw[prow * 72 + ((ch ^ sw) << 3) + (l15 & 7)] = f2bf(p);
                }
                l_i[i] += rs;
            }
            asm volatile("s_waitcnt lgkmcnt(0)" ::: "memory");
            __builtin_amdgcn_sched_barrier(0);
#pragma unroll
            for (int kst = 0; kst < 2; ++kst) {
                int pchs = (kst * 4 + l4) ^ ((l15 >> 1) & 3);
                bf16x8 pf = *(const bf16x8*)&Pw[l15 * 72 + pchs * 8];
                int kst2 = hf * 2 + kst;
#pragma unroll
                for (int nf = 0; nf < 8; ++nf) {
                    int d = nf * 16 + l15;
                    int vch = (kst2 * 4 + l4) ^ (d & 7);
                    bf16x8 vf = *(const bf16x8*)&VL[d * 128 + vch * 8];
                    o[nf] = __builtin_amdgcn_mfma_f32_16x16x32_bf16(pf, vf, o[nf], 0, 0, 0);
                }
            }
        }
    }
    write_ctx();
}

extern "C" void kernel_launch(void* const* d_in, const int* in_sizes, int n_in,
                              void* d_out, int out_size, void* d_ws, size_t ws_size,
                              hipStream_t stream) {
    const float* hidden = (const float*)d_in[0];   // fp32 (per reference dtype)
    // d_in[1] = sequence_mask (unused by reference math: all-ones + causal)
    const float* Wqkv = (const float*)d_in[2];     // fp32
    const float* Wo = (const float*)d_in[3];       // fp32
    float* out = (float*)d_out;                    // fp32 output
    char* ws = (char*)d_ws;

    // ws layout (bytes), liveness audited (QKV stays live through attn as Q source):
    //   QKV     [0,        25165824)  gemm1 -> attn(Q) / mid(K,V)
    //   WqkvT   [25165824, 75497472)  pre -> gemm1 (dead after gemm1)
    //   Kb      [25165824, 29360128)  mid -> attn           (in dead WqkvT)
    //   VTg     [29360128, 33554432)  mid -> attn           (in dead WqkvT)
    //   WoT     [34603008, 68157440)  mid -> gemm2          (in dead WqkvT)
    //   ctx     [68157440, 84934656)  attn -> gemm2         (dead WqkvT + dead hiddenB)
    //   hiddenB [75497472, 92274688)  pre -> gemm1 (dead after gemm1)
    //   tab     [92274688, 93323264)  pre -> mid+attn (disjoint from all live regions)
    u16* QKV     = (u16*)(ws + 0);
    u16* WqkvT   = (u16*)(ws + 25165824);
    u16* Kb      = (u16*)(ws + 25165824);
    u16* VTg     = (u16*)(ws + 29360128);
    u16* WoT     = (u16*)(ws + 34603008);
    u16* ctx     = (u16*)(ws + 68157440);
    u16* hiddenB = (u16*)(ws + 75497472);
    float* tab   = (float*)(ws + 92274688);  // disjoint from everything live

    pre_fused_k<<<14848, 256, 0, stream>>>(hidden, hiddenB, Wqkv, WqkvT, tab);
    gemm1_big_k<<<256, 512, 0, stream>>>(hiddenB, WqkvT, QKV);
    mid_fused_k<<<5632, 256, 0, stream>>>(QKV, tab, Kb, VTg, Wo, WoT);
    attn_k<<<dim3(8, 32), 512, 0, stream>>>(QKV, Kb, VTg, tab, ctx);
    gemm2_big_k<<<256, 512, 0, stream>>>(ctx, WoT, out);
}